// Round 8
// baseline (343.498 us; speedup 1.0000x reference)
//
#include <hip/hip_runtime.h>
#include <math.h>
#include <float.h>

constexpr int D = 128;       // in_channels
constexpr int B = 512;       // batch_size (graphs)
constexpr int STEPS = 3;
constexpr int NW_IH = 3 * D * 2 * D;   // 98304 elems, Wih [3D][2D]
constexpr int NW_HH = 3 * D * D;       // 49152 elems, Whh [3D][D]
constexpr float NEG_HUGE = -3.402823466e38f;   // -FLT_MAX sentinel (finite: no NaN paths)

__device__ __forceinline__ float sigmoidf_(float x) { return 1.f / (1.f + __expf(-x)); }
// bf16 pair unpack from a uint: low halfword / high halfword -> float (exact)
__device__ __forceinline__ float bflo(unsigned int u) { return __uint_as_float(u << 16); }
__device__ __forceinline__ float bfhi(unsigned int u) { return __uint_as_float(u & 0xffff0000u); }
__device__ __forceinline__ unsigned short f2bf_rn(float f) {
    unsigned int u = __float_as_uint(f);
    u += 0x7fffu + ((u >> 16) & 1u);    // round-to-nearest-even
    return (unsigned short)(u >> 16);
}
__device__ __forceinline__ float4 ld4(const float* p) { return *(const float4*)p; }
__device__ __forceinline__ int imin_(int a, int b) { return a < b ? a : b; }

// ---------------------------------------------------------------------------
// K0 (prep): weights fp32 -> bf16 (RN), row-major, plus segment bounds via
// binary search on sorted batch[] (seg[g] = first index with batch[i] >= g).
// ---------------------------------------------------------------------------
__global__ __launch_bounds__(256) void k_prep(const float* __restrict__ Wih,
        const float* __restrict__ Whh, const int* __restrict__ batch, int n,
        unsigned short* __restrict__ wih_bf, unsigned short* __restrict__ whh_bf,
        int* __restrict__ seg) {
    int i = blockIdx.x * blockDim.x + threadIdx.x;
    if (i < NW_IH) wih_bf[i] = f2bf_rn(Wih[i]);
    else if (i < NW_IH + NW_HH) whh_bf[i - NW_IH] = f2bf_rn(Whh[i - NW_IH]);
    if (i <= B) {
        int lo = 0, hi = n;
        while (lo < hi) { int mid = (lo + hi) >> 1; if (batch[mid] < i) lo = mid + 1; else hi = mid; }
        seg[i] = lo;
    }
}

// ---------------------------------------------------------------------------
// K1 (fused Set2Set): one block of 512 threads (8 waves) per graph.
// R7 post-mortem: fp16 x-compression attacked a non-bottleneck (steps 1-2
// are L3-served and latency-bound, not HBM-bound). R5's 94us decomposes as:
//   GRU ~15us/step = TA-request-bound (36.9K divergent line-requests/CU at
//   ~1/cy -> layout/wave changes can't help; R6 confirmed), attention
//   ~19us/step = LATENCY-bound at only 2 waves/SIMD (occupancy 20%).
// R8 = R5 structure with 512-thread blocks -> 16 waves/CU = 4 waves/SIMD:
//   * 32 node-groups x 16 lanes, trips stride 128 nodes (FT ~ 3), same
//     depth-2 masked-tail pipeline, same per-thread register state.
//   * __launch_bounds__(512,4): VGPR cap 128 (R5 used 120 -> fits).
//   * GRU: 384 threads, one row each, 3 interleaved load streams (TA total
//     unchanged -> same GRU time; conservative).
//   * combine: 5-shfl tree over 32 (m,l) partials; rpart[8][D].
// ---------------------------------------------------------------------------
struct Trip { float4 a0, a1, b0, b1, c0, c1, d0, d1; };

__global__ __launch_bounds__(512, 4) void k_set2set(
        const float* __restrict__ x,
        const unsigned short* __restrict__ wih_bf,
        const unsigned short* __restrict__ whh_bf,
        const float* __restrict__ bih, const float* __restrict__ bhh,
        const int* __restrict__ seg, float* __restrict__ out) {
    __shared__ __align__(16) float s_q[2 * D];    // q_star: [q | r]
    __shared__ __align__(16) float s_h[D];
    __shared__ float s_gi[3 * D], s_gh[3 * D];
    __shared__ float sm[32], sl[32];
    __shared__ __align__(16) float rpart[8][D];   // 4 KB

    const int b = blockIdx.x;
    const int tid = threadIdx.x;
    const int start = seg[b], end = seg[b + 1];
    const int g = tid >> 4;               // node-group id 0..31
    const int s = tid & 15;               // sublane: cols [4s,4s+4) & [64+4s,64+4s+4)
    const int s4 = s * 4;

    const int len = end - start;
    const int FT = (len + 127) >> 7;      // trips incl. masked last (128 nodes/trip)
    const int gbase = start + g;
    const int eclamp = (len > 0) ? end - 1 : start;

    float m_run, l_run;
    float4 acc0, acc1;
    float4 q0, q1;
    Trip T0_, T1_;

    auto load_trip = [&](Trip& T, int t) {
        const int n0 = gbase + (t << 7);
        const float* p0 = x + ((size_t)imin_(n0,      eclamp) << 7) + s4;
        const float* p1 = x + ((size_t)imin_(n0 + 32, eclamp) << 7) + s4;
        const float* p2 = x + ((size_t)imin_(n0 + 64, eclamp) << 7) + s4;
        const float* p3 = x + ((size_t)imin_(n0 + 96, eclamp) << 7) + s4;
        T.a0 = ld4(p0); T.a1 = ld4(p0 + 64);
        T.b0 = ld4(p1); T.b1 = ld4(p1 + 64);
        T.c0 = ld4(p2); T.c1 = ld4(p2 + 64);
        T.d0 = ld4(p3); T.d1 = ld4(p3 + 64);
    };
    auto dot8 = [&](const float4& lo, const float4& hi) {
        float p = lo.x * q0.x;
        p = fmaf(lo.y, q0.y, p); p = fmaf(lo.z, q0.z, p); p = fmaf(lo.w, q0.w, p);
        p = fmaf(hi.x, q1.x, p); p = fmaf(hi.y, q1.y, p);
        p = fmaf(hi.z, q1.z, p); p = fmaf(hi.w, q1.w, p);
        return p;
    };
    auto compute_core = [&](const Trip& T, bool masked, int t) {
        float p0 = dot8(T.a0, T.a1);
        float p1 = dot8(T.b0, T.b1);
        float p2 = dot8(T.c0, T.c1);
        float p3 = dot8(T.d0, T.d1);
        p0 += __shfl_xor(p0, 1, 64); p1 += __shfl_xor(p1, 1, 64);
        p2 += __shfl_xor(p2, 1, 64); p3 += __shfl_xor(p3, 1, 64);
        p0 += __shfl_xor(p0, 2, 64); p1 += __shfl_xor(p1, 2, 64);
        p2 += __shfl_xor(p2, 2, 64); p3 += __shfl_xor(p3, 2, 64);
        p0 += __shfl_xor(p0, 4, 64); p1 += __shfl_xor(p1, 4, 64);
        p2 += __shfl_xor(p2, 4, 64); p3 += __shfl_xor(p3, 4, 64);
        p0 += __shfl_xor(p0, 8, 64); p1 += __shfl_xor(p1, 8, 64);
        p2 += __shfl_xor(p2, 8, 64); p3 += __shfl_xor(p3, 8, 64);
        bool m0 = true, m1 = true, m2 = true, m3 = true;
        float h0 = p0, h1 = p1, h2 = p2, h3 = p3;
        if (masked) {
            const int n0 = gbase + (t << 7);
            m0 = n0 < end; m1 = n0 + 32 < end; m2 = n0 + 64 < end; m3 = n0 + 96 < end;
            h0 = m0 ? p0 : NEG_HUGE; h1 = m1 ? p1 : NEG_HUGE;
            h2 = m2 ? p2 : NEG_HUGE; h3 = m3 ? p3 : NEG_HUGE;
        }
        float nm = fmaxf(m_run, fmaxf(fmaxf(h0, h1), fmaxf(h2, h3)));
        float sc = __expf(m_run - nm);            // 0 while m_run sentinel
        float e0 = __expf(p0 - nm), e1 = __expf(p1 - nm);
        float e2 = __expf(p2 - nm), e3 = __expf(p3 - nm);
        if (masked) {
            e0 = m0 ? e0 : 0.f; e1 = m1 ? e1 : 0.f;
            e2 = m2 ? e2 : 0.f; e3 = m3 ? e3 : 0.f;
        }
        l_run = fmaf(l_run, sc, (e0 + e1) + (e2 + e3));
        acc0.x = fmaf(acc0.x, sc, fmaf(e0, T.a0.x, fmaf(e1, T.b0.x, fmaf(e2, T.c0.x, e3 * T.d0.x))));
        acc0.y = fmaf(acc0.y, sc, fmaf(e0, T.a0.y, fmaf(e1, T.b0.y, fmaf(e2, T.c0.y, e3 * T.d0.y))));
        acc0.z = fmaf(acc0.z, sc, fmaf(e0, T.a0.z, fmaf(e1, T.b0.z, fmaf(e2, T.c0.z, e3 * T.d0.z))));
        acc0.w = fmaf(acc0.w, sc, fmaf(e0, T.a0.w, fmaf(e1, T.b0.w, fmaf(e2, T.c0.w, e3 * T.d0.w))));
        acc1.x = fmaf(acc1.x, sc, fmaf(e0, T.a1.x, fmaf(e1, T.b1.x, fmaf(e2, T.c1.x, e3 * T.d1.x))));
        acc1.y = fmaf(acc1.y, sc, fmaf(e0, T.a1.y, fmaf(e1, T.b1.y, fmaf(e2, T.c1.y, e3 * T.d1.y))));
        acc1.z = fmaf(acc1.z, sc, fmaf(e0, T.a1.z, fmaf(e1, T.b1.z, fmaf(e2, T.c1.z, e3 * T.d1.z))));
        acc1.w = fmaf(acc1.w, sc, fmaf(e0, T.a1.w, fmaf(e1, T.b1.w, fmaf(e2, T.c1.w, e3 * T.d1.w))));
        m_run = nm;
    };
    auto compute  = [&](const Trip& T)        { compute_core(T, false, 0); };
    auto computeM = [&](const Trip& T, int t) { compute_core(T, true,  t); };

    if (tid < 2 * D) s_q[tid] = 0.f;
    if (tid < D) s_h[tid] = 0.f;
    __syncthreads();

    for (int step = 0; step < STEPS; ++step) {
        // prefetch trip 0 of x under the GRU (x is step-invariant; no LDS dep)
        if (FT > 0) load_trip(T0_, 0);

        if (step == 0) {
            // q_star = 0 and h = 0: gi = b_ih, gh = b_hh exactly -> skip matvec
            if (tid < 3 * D) { s_gi[tid] = bih[tid]; s_gh[tid] = bhh[tid]; }
        } else if (tid < 384) {
            // ---- GRU gate row r = tid; 3 interleaved load streams ----
            const int r = tid;
            float gi = bih[r], gh = bhh[r];
            const uint4* w = (const uint4*)(wih_bf + (size_t)r * (2 * D));  // 32 chunks
            const uint4* v = (const uint4*)(whh_bf + (size_t)r * D);        // 16 chunks
            const float4* q4 = (const float4*)s_q;
            const float4* h4 = (const float4*)s_h;
#pragma unroll 4
            for (int c = 0; c < 16; ++c) {
                uint4 wa = w[c];            // Wih cols 8c..8c+7
                uint4 wb = w[c + 16];       // Wih cols 128+8c..128+8c+7
                uint4 va = v[c];            // Whh cols 8c..8c+7
                float4 qa = q4[2 * c], qb = q4[2 * c + 1];
                float4 qc = q4[32 + 2 * c], qd = q4[33 + 2 * c];
                float4 ha = h4[2 * c], hb = h4[2 * c + 1];
                gi = fmaf(bflo(wa.x), qa.x, gi); gi = fmaf(bfhi(wa.x), qa.y, gi);
                gi = fmaf(bflo(wa.y), qa.z, gi); gi = fmaf(bfhi(wa.y), qa.w, gi);
                gi = fmaf(bflo(wa.z), qb.x, gi); gi = fmaf(bfhi(wa.z), qb.y, gi);
                gi = fmaf(bflo(wa.w), qb.z, gi); gi = fmaf(bfhi(wa.w), qb.w, gi);
                gi = fmaf(bflo(wb.x), qc.x, gi); gi = fmaf(bfhi(wb.x), qc.y, gi);
                gi = fmaf(bflo(wb.y), qc.z, gi); gi = fmaf(bfhi(wb.y), qc.w, gi);
                gi = fmaf(bflo(wb.z), qd.x, gi); gi = fmaf(bfhi(wb.z), qd.y, gi);
                gi = fmaf(bflo(wb.w), qd.z, gi); gi = fmaf(bfhi(wb.w), qd.w, gi);
                gh = fmaf(bflo(va.x), ha.x, gh); gh = fmaf(bfhi(va.x), ha.y, gh);
                gh = fmaf(bflo(va.y), ha.z, gh); gh = fmaf(bfhi(va.y), ha.w, gh);
                gh = fmaf(bflo(va.z), hb.x, gh); gh = fmaf(bfhi(va.z), hb.y, gh);
                gh = fmaf(bflo(va.w), hb.z, gh); gh = fmaf(bfhi(va.w), hb.w, gh);
            }
            s_gi[r] = gi; s_gh[r] = gh;
        }
        __syncthreads();
        // ---- GRU epilogue (biases already inside s_gi/s_gh) ----
        if (tid < D) {
            const int t = tid;
            float r  = sigmoidf_(s_gi[t] + s_gh[t]);
            float z  = sigmoidf_(s_gi[D + t] + s_gh[D + t]);
            float nn = tanhf(s_gi[2 * D + t] + r * s_gh[2 * D + t]);
            float hn = (1.f - z) * nn + z * s_h[t];
            s_h[t] = hn;
            s_q[t] = hn;                  // q part of q_star
        }
        __syncthreads();

        // ---- flash attention, depth-2 pipeline, masked tail ----
        q0 = ((const float4*)s_h)[s];          // cols 4s..4s+3
        q1 = ((const float4*)s_h)[16 + s];     // cols 64+4s..64+4s+3
        m_run = NEG_HUGE; l_run = 0.f;
        acc0 = make_float4(0.f, 0.f, 0.f, 0.f);
        acc1 = make_float4(0.f, 0.f, 0.f, 0.f);

        if (FT > 0) {
            if (FT > 1) load_trip(T1_, 1);
            int t = 0;
            for (; t + 2 < FT; t += 2) {       // trips t, t+1 both full here
                compute(T0_); load_trip(T0_, t + 2);
                compute(T1_); if (t + 3 < FT) load_trip(T1_, t + 3);
            }
            if (t == FT - 1) computeM(T0_, t);
            else { compute(T0_); computeM(T1_, t + 1); }   // t+1 == FT-1
        }

        if (s == 0) { sm[g] = m_run; sl[g] = l_run; }
        __syncthreads();

        // ---- combine 32 group partials (every lane, 5-shfl tree) ----
        {
            const int l32i = tid & 31;
            const float mv = sm[l32i];
            const float lv = sl[l32i];
            float M = mv;
            M = fmaxf(M, __shfl_xor(M, 1, 64));
            M = fmaxf(M, __shfl_xor(M, 2, 64));
            M = fmaxf(M, __shfl_xor(M, 4, 64));
            M = fmaxf(M, __shfl_xor(M, 8, 64));
            M = fmaxf(M, __shfl_xor(M, 16, 64));
            float term = lv * __expf(mv - M);     // sentinel-safe: lv==0 there
            term += __shfl_xor(term, 1, 64);
            term += __shfl_xor(term, 2, 64);
            term += __shfl_xor(term, 4, 64);
            term += __shfl_xor(term, 8, 64);
            term += __shfl_xor(term, 16, 64);
            const float inv = 1.f / (term + 1e-16f);
            const float fac = __expf(m_run - M) * inv;  // sentinel-safe
            acc0.x *= fac; acc0.y *= fac; acc0.z *= fac; acc0.w *= fac;
            acc1.x *= fac; acc1.y *= fac; acc1.z *= fac; acc1.w *= fac;
        }
        // ---- sum the 4 groups within each wave (lanes s, s^16, s^32, s^48) --
        acc0.x += __shfl_xor(acc0.x, 16, 64); acc0.y += __shfl_xor(acc0.y, 16, 64);
        acc0.z += __shfl_xor(acc0.z, 16, 64); acc0.w += __shfl_xor(acc0.w, 16, 64);
        acc1.x += __shfl_xor(acc1.x, 16, 64); acc1.y += __shfl_xor(acc1.y, 16, 64);
        acc1.z += __shfl_xor(acc1.z, 16, 64); acc1.w += __shfl_xor(acc1.w, 16, 64);
        acc0.x += __shfl_xor(acc0.x, 32, 64); acc0.y += __shfl_xor(acc0.y, 32, 64);
        acc0.z += __shfl_xor(acc0.z, 32, 64); acc0.w += __shfl_xor(acc0.w, 32, 64);
        acc1.x += __shfl_xor(acc1.x, 32, 64); acc1.y += __shfl_xor(acc1.y, 32, 64);
        acc1.z += __shfl_xor(acc1.z, 32, 64); acc1.w += __shfl_xor(acc1.w, 32, 64);

        const int wv = tid >> 6;          // wave id 0..7
        if ((tid & 63) < 16) {
            *(float4*)&rpart[wv][s4]      = acc0;
            *(float4*)&rpart[wv][64 + s4] = acc1;
        }
        __syncthreads();
        if (tid < D) {
            float v = ((rpart[0][tid] + rpart[1][tid]) + (rpart[2][tid] + rpart[3][tid]))
                    + ((rpart[4][tid] + rpart[5][tid]) + (rpart[6][tid] + rpart[7][tid]));
            s_q[D + tid] = v;             // r part of q_star (already /L)
        }
        __syncthreads();                  // s_q complete for next GRU / output
    }

    // ---- write q_star row (s_q is exactly [q | r]) ----
    if (tid < 2 * D) out[(size_t)b * (2 * D) + tid] = s_q[tid];
}

// ---------------------------------------------------------------------------
extern "C" void kernel_launch(void* const* d_in, const int* in_sizes, int n_in,
                              void* d_out, int out_size, void* d_ws, size_t ws_size,
                              hipStream_t stream) {
    const float* x    = (const float*)d_in[0];
    const int*   batch= (const int*)d_in[1];
    // d_in[2] = batch_size scalar (fixed at B=512 compile time)
    const float* Wih  = (const float*)d_in[3];
    const float* Whh  = (const float*)d_in[4];
    const float* bih  = (const float*)d_in[5];
    const float* bhh  = (const float*)d_in[6];
    const int n = in_sizes[0] / D;        // 200000

    // workspace: seg (4 KB pad) | wih_bf (192 KB) | whh_bf (96 KB)
    char* ws = (char*)d_ws;
    int* seg = (int*)ws;
    unsigned short* wih_bf = (unsigned short*)(ws + 4096);
    unsigned short* whh_bf = (unsigned short*)(ws + 4096 + (size_t)NW_IH * 2);

    const int total = NW_IH + NW_HH;      // 147456 >= B+1, covers seg too
    k_prep<<<(total + 255) / 256, 256, 0, stream>>>(Wih, Whh, batch, n, wih_bf, whh_bf, seg);
    k_set2set<<<B, 512, 0, stream>>>(x, wih_bf, whh_bf, bih, bhh, seg, (float*)d_out);
}

// Round 9
// 218.259 us; speedup vs baseline: 1.5738x; 1.5738x over previous
//
#include <hip/hip_runtime.h>
#include <math.h>
#include <float.h>

constexpr int D = 128;       // in_channels
constexpr int B = 512;       // batch_size (graphs)
constexpr int STEPS = 3;
constexpr int NW_IH = 3 * D * 2 * D;   // 98304 elems, Wih [3D][2D]
constexpr int NW_HH = 3 * D * D;       // 49152 elems, Whh [3D][D]
constexpr float NEG_HUGE = -3.402823466e38f;   // -FLT_MAX sentinel (finite: no NaN paths)

typedef float f32x4 __attribute__((ext_vector_type(4)));
typedef __attribute__((address_space(1))) unsigned int gu32;
typedef __attribute__((address_space(3))) unsigned int lu32;
typedef __attribute__((address_space(3))) const unsigned char lchar;

__device__ __forceinline__ float sigmoidf_(float x) { return 1.f / (1.f + __expf(-x)); }
// bf16 pair unpack from a uint: low halfword / high halfword -> float (exact)
__device__ __forceinline__ float bflo(unsigned int u) { return __uint_as_float(u << 16); }
__device__ __forceinline__ float bfhi(unsigned int u) { return __uint_as_float(u & 0xffff0000u); }
__device__ __forceinline__ unsigned short f2bf_rn(float f) {
    unsigned int u = __float_as_uint(f);
    u += 0x7fffu + ((u >> 16) & 1u);    // round-to-nearest-even
    return (unsigned short)(u >> 16);
}
__device__ __forceinline__ int imin_(int a, int b) { return a < b ? a : b; }

// async 16B/lane global->LDS; LDS dest is wave-uniform base, HW adds lane*16
__device__ __forceinline__ void gll16(const float* g, float* l) {
    __builtin_amdgcn_global_load_lds((const gu32*)g, (lu32*)l, 16, 0, 0);
}
// byte offset of an LDS pointer (AS3 pointers are 32-bit)
__device__ __forceinline__ unsigned lds_lo(const void* p) {
    return (unsigned)(unsigned long long)(lchar*)p;
}
#define WAITVM8() asm volatile("s_waitcnt vmcnt(8)" ::: "memory")
#define WAITVM0() asm volatile("s_waitcnt vmcnt(0)" ::: "memory")

// ---------------------------------------------------------------------------
// K0 (prep): weights fp32 -> bf16 (RN), row-major, plus segment bounds via
// binary search on sorted batch[] (seg[g] = first index with batch[i] >= g).
// ---------------------------------------------------------------------------
__global__ __launch_bounds__(256) void k_prep(const float* __restrict__ Wih,
        const float* __restrict__ Whh, const int* __restrict__ batch, int n,
        unsigned short* __restrict__ wih_bf, unsigned short* __restrict__ whh_bf,
        int* __restrict__ seg) {
    int i = blockIdx.x * blockDim.x + threadIdx.x;
    if (i < NW_IH) wih_bf[i] = f2bf_rn(Wih[i]);
    else if (i < NW_IH + NW_HH) whh_bf[i - NW_IH] = f2bf_rn(Whh[i - NW_IH]);
    if (i <= B) {
        int lo = 0, hi = n;
        while (lo < hi) { int mid = (lo + hi) >> 1; if (batch[mid] < i) lo = mid + 1; else hi = mid; }
        seg[i] = lo;
    }
}

// ---------------------------------------------------------------------------
// K1 (fused Set2Set): one block of 256 threads (4 waves) per graph.
// R8 post-mortem: occupancy-via-VGPR is a wall (allocator targets 64/128
// tiers; our state needs 128). R5's attention sits AT the Little's-law
// in-flight-bytes ceiling (~8KB/CU vs ~900cy L3 latency). R9 raises
// in-flight with LDS, not VGPRs:
//   * per wave: two private 8KB LDS trip-buffers; global_load_lds (16B/lane,
//     async, zero VGPR) stages trip t+2 while computing trip t.
//   * inline-asm ds_read_b128 x8 + lgkmcnt(0) pulls the resident buffer into
//     ONE 32-reg Trip (register pressure DROPS vs R5's two Trips).
//   * counted s_waitcnt vmcnt(8) in steady state (never 0 mid-loop);
//     wave-private buffers -> no barriers in the loop.
//   * prologue stages trips 0,1 before the GRU; the GRU-epilogue barrier's
//     vmcnt(0) drain makes them resident for free.
// GRU / combine / masked tail: byte-for-byte R5 (verified 94us).
// ---------------------------------------------------------------------------
struct TripV { f32x4 a0, a1, b0, b1, c0, c1, d0, d1; };

__device__ __forceinline__ TripV lds_read_trip(unsigned la) {
    TripV T;
    asm volatile(
        "ds_read_b128 %0, %8 offset:0\n\t"
        "ds_read_b128 %1, %8 offset:1024\n\t"
        "ds_read_b128 %2, %8 offset:2048\n\t"
        "ds_read_b128 %3, %8 offset:3072\n\t"
        "ds_read_b128 %4, %8 offset:4096\n\t"
        "ds_read_b128 %5, %8 offset:5120\n\t"
        "ds_read_b128 %6, %8 offset:6144\n\t"
        "ds_read_b128 %7, %8 offset:7168\n\t"
        "s_waitcnt lgkmcnt(0)"
        : "=&v"(T.a0), "=&v"(T.a1), "=&v"(T.b0), "=&v"(T.b1),
          "=&v"(T.c0), "=&v"(T.c1), "=&v"(T.d0), "=&v"(T.d1)
        : "v"(la));
    __builtin_amdgcn_sched_barrier(0);
    return T;
}

__global__ __launch_bounds__(256, 2) void k_set2set(
        const float* __restrict__ x,
        const unsigned short* __restrict__ wih_bf,
        const unsigned short* __restrict__ whh_bf,
        const float* __restrict__ bih, const float* __restrict__ bhh,
        const int* __restrict__ seg, float* __restrict__ out) {
    __shared__ __align__(16) float s_q[2 * D];    // q_star: [q | r]
    __shared__ __align__(16) float s_h[D];
    __shared__ float s_gi[3 * D], s_gh[3 * D];
    __shared__ float sm[16], sl[16];
    __shared__ __align__(16) float rpart[4][D];   // 2 KB
    __shared__ __align__(16) float s_bufA[4][2048];   // 32 KB: per-wave trip buf A
    __shared__ __align__(16) float s_bufB[4][2048];   // 32 KB: per-wave trip buf B

    const int b = blockIdx.x;
    const int tid = threadIdx.x;
    const int start = seg[b], end = seg[b + 1];
    const int g = tid >> 4;               // node-group id 0..15
    const int s = tid & 15;               // sublane: cols [4s,4s+4) & [64+4s,64+4s+4)
    const int s4 = s * 4;
    const int wv = tid >> 6;              // wave id 0..3
    const int lane = tid & 63;

    const int len = end - start;
    const int FT = (len + 63) >> 6;       // trips incl. masked last
    const int gbase = start + g;
    const int eclamp = (len > 0) ? end - 1 : start;

    float* bufA = &s_bufA[wv][0];
    float* bufB = &s_bufB[wv][0];
    const unsigned laA = lds_lo(bufA) + lane * 16;
    const unsigned laB = lds_lo(bufB) + lane * 16;

    float m_run, l_run;
    float4 acc0, acc1;
    float4 q0, q1;

    auto stage_trip = [&](float* buf, int t) {
        const int n0 = gbase + (t << 6);
        const float* p0 = x + ((size_t)imin_(n0,      eclamp) << 7) + s4;
        const float* p1 = x + ((size_t)imin_(n0 + 16, eclamp) << 7) + s4;
        const float* p2 = x + ((size_t)imin_(n0 + 32, eclamp) << 7) + s4;
        const float* p3 = x + ((size_t)imin_(n0 + 48, eclamp) << 7) + s4;
        gll16(p0,      buf);
        gll16(p0 + 64, buf + 256);
        gll16(p1,      buf + 512);
        gll16(p1 + 64, buf + 768);
        gll16(p2,      buf + 1024);
        gll16(p2 + 64, buf + 1280);
        gll16(p3,      buf + 1536);
        gll16(p3 + 64, buf + 1792);
    };
    auto dot8 = [&](const f32x4& lo, const f32x4& hi) {
        float p = lo.x * q0.x;
        p = fmaf(lo.y, q0.y, p); p = fmaf(lo.z, q0.z, p); p = fmaf(lo.w, q0.w, p);
        p = fmaf(hi.x, q1.x, p); p = fmaf(hi.y, q1.y, p);
        p = fmaf(hi.z, q1.z, p); p = fmaf(hi.w, q1.w, p);
        return p;
    };
    auto compute_core = [&](const TripV& T, bool masked, int t) {
        float p0 = dot8(T.a0, T.a1);
        float p1 = dot8(T.b0, T.b1);
        float p2 = dot8(T.c0, T.c1);
        float p3 = dot8(T.d0, T.d1);
        p0 += __shfl_xor(p0, 1, 64); p1 += __shfl_xor(p1, 1, 64);
        p2 += __shfl_xor(p2, 1, 64); p3 += __shfl_xor(p3, 1, 64);
        p0 += __shfl_xor(p0, 2, 64); p1 += __shfl_xor(p1, 2, 64);
        p2 += __shfl_xor(p2, 2, 64); p3 += __shfl_xor(p3, 2, 64);
        p0 += __shfl_xor(p0, 4, 64); p1 += __shfl_xor(p1, 4, 64);
        p2 += __shfl_xor(p2, 4, 64); p3 += __shfl_xor(p3, 4, 64);
        p0 += __shfl_xor(p0, 8, 64); p1 += __shfl_xor(p1, 8, 64);
        p2 += __shfl_xor(p2, 8, 64); p3 += __shfl_xor(p3, 8, 64);
        bool m0 = true, m1 = true, m2 = true, m3 = true;
        float h0 = p0, h1 = p1, h2 = p2, h3 = p3;
        if (masked) {
            const int n0 = gbase + (t << 6);
            m0 = n0 < end; m1 = n0 + 16 < end; m2 = n0 + 32 < end; m3 = n0 + 48 < end;
            h0 = m0 ? p0 : NEG_HUGE; h1 = m1 ? p1 : NEG_HUGE;
            h2 = m2 ? p2 : NEG_HUGE; h3 = m3 ? p3 : NEG_HUGE;
        }
        float nm = fmaxf(m_run, fmaxf(fmaxf(h0, h1), fmaxf(h2, h3)));
        float sc = __expf(m_run - nm);            // 0 while m_run sentinel
        float e0 = __expf(p0 - nm), e1 = __expf(p1 - nm);
        float e2 = __expf(p2 - nm), e3 = __expf(p3 - nm);
        if (masked) {
            e0 = m0 ? e0 : 0.f; e1 = m1 ? e1 : 0.f;
            e2 = m2 ? e2 : 0.f; e3 = m3 ? e3 : 0.f;
        }
        l_run = fmaf(l_run, sc, (e0 + e1) + (e2 + e3));
        acc0.x = fmaf(acc0.x, sc, fmaf(e0, T.a0.x, fmaf(e1, T.b0.x, fmaf(e2, T.c0.x, e3 * T.d0.x))));
        acc0.y = fmaf(acc0.y, sc, fmaf(e0, T.a0.y, fmaf(e1, T.b0.y, fmaf(e2, T.c0.y, e3 * T.d0.y))));
        acc0.z = fmaf(acc0.z, sc, fmaf(e0, T.a0.z, fmaf(e1, T.b0.z, fmaf(e2, T.c0.z, e3 * T.d0.z))));
        acc0.w = fmaf(acc0.w, sc, fmaf(e0, T.a0.w, fmaf(e1, T.b0.w, fmaf(e2, T.c0.w, e3 * T.d0.w))));
        acc1.x = fmaf(acc1.x, sc, fmaf(e0, T.a1.x, fmaf(e1, T.b1.x, fmaf(e2, T.c1.x, e3 * T.d1.x))));
        acc1.y = fmaf(acc1.y, sc, fmaf(e0, T.a1.y, fmaf(e1, T.b1.y, fmaf(e2, T.c1.y, e3 * T.d1.y))));
        acc1.z = fmaf(acc1.z, sc, fmaf(e0, T.a1.z, fmaf(e1, T.b1.z, fmaf(e2, T.c1.z, e3 * T.d1.z))));
        acc1.w = fmaf(acc1.w, sc, fmaf(e0, T.a1.w, fmaf(e1, T.b1.w, fmaf(e2, T.c1.w, e3 * T.d1.w))));
        m_run = nm;
    };
    auto compute  = [&](const TripV& T)        { compute_core(T, false, 0); };
    auto computeM = [&](const TripV& T, int t) { compute_core(T, true,  t); };

    if (tid < 2 * D) s_q[tid] = 0.f;
    if (tid < D) s_h[tid] = 0.f;
    __syncthreads();

    for (int step = 0; step < STEPS; ++step) {
        // prologue: stage trips 0,1 async (x step-invariant; no LDS-state dep).
        // The GRU-epilogue barrier's vmcnt(0) drain makes them resident for free.
        if (FT > 0) stage_trip(bufA, 0);
        if (FT > 1) stage_trip(bufB, 1);

        if (step == 0) {
            // q_star = 0 and h = 0: gi = b_ih, gh = b_hh exactly -> skip matvec
            for (int i = tid; i < 3 * D; i += 256) { s_gi[i] = bih[i]; s_gh[i] = bhh[i]; }
        } else if (tid < 192) {
            // ---- GRU gate rows: threads 0..191, rows 2t and 2t+1 (ILP 2) ----
            const int r0 = tid * 2, r1 = r0 + 1;
            float gi0 = bih[r0], gi1 = bih[r1];
            float gh0 = bhh[r0], gh1 = bhh[r1];
            const float4* q4 = (const float4*)s_q;
            const float4* h4 = (const float4*)s_h;
            const uint4* w0 = (const uint4*)(wih_bf + (size_t)r0 * (2 * D));
            const uint4* w1 = (const uint4*)(wih_bf + (size_t)r1 * (2 * D));
#pragma unroll 4
            for (int c = 0; c < 32; ++c) {        // 256 cols of Wih, 8/iter
                uint4 wa = w0[c], wb = w1[c];
                float4 qa = q4[2 * c], qb = q4[2 * c + 1];
                gi0 = fmaf(bflo(wa.x), qa.x, gi0); gi0 = fmaf(bfhi(wa.x), qa.y, gi0);
                gi0 = fmaf(bflo(wa.y), qa.z, gi0); gi0 = fmaf(bfhi(wa.y), qa.w, gi0);
                gi0 = fmaf(bflo(wa.z), qb.x, gi0); gi0 = fmaf(bfhi(wa.z), qb.y, gi0);
                gi0 = fmaf(bflo(wa.w), qb.z, gi0); gi0 = fmaf(bfhi(wa.w), qb.w, gi0);
                gi1 = fmaf(bflo(wb.x), qa.x, gi1); gi1 = fmaf(bfhi(wb.x), qa.y, gi1);
                gi1 = fmaf(bflo(wb.y), qa.z, gi1); gi1 = fmaf(bfhi(wb.y), qa.w, gi1);
                gi1 = fmaf(bflo(wb.z), qb.x, gi1); gi1 = fmaf(bfhi(wb.z), qb.y, gi1);
                gi1 = fmaf(bflo(wb.w), qb.z, gi1); gi1 = fmaf(bfhi(wb.w), qb.w, gi1);
            }
            const uint4* v0 = (const uint4*)(whh_bf + (size_t)r0 * D);
            const uint4* v1 = (const uint4*)(whh_bf + (size_t)r1 * D);
#pragma unroll 4
            for (int c = 0; c < 16; ++c) {        // 128 cols of Whh
                uint4 wa = v0[c], wb = v1[c];
                float4 ha = h4[2 * c], hb = h4[2 * c + 1];
                gh0 = fmaf(bflo(wa.x), ha.x, gh0); gh0 = fmaf(bfhi(wa.x), ha.y, gh0);
                gh0 = fmaf(bflo(wa.y), ha.z, gh0); gh0 = fmaf(bfhi(wa.y), ha.w, gh0);
                gh0 = fmaf(bflo(wa.z), hb.x, gh0); gh0 = fmaf(bfhi(wa.z), hb.y, gh0);
                gh0 = fmaf(bflo(wa.w), hb.z, gh0); gh0 = fmaf(bfhi(wa.w), hb.w, gh0);
                gh1 = fmaf(bflo(wb.x), ha.x, gh1); gh1 = fmaf(bfhi(wb.x), ha.y, gh1);
                gh1 = fmaf(bflo(wb.y), ha.z, gh1); gh1 = fmaf(bfhi(wb.y), ha.w, gh1);
                gh1 = fmaf(bflo(wb.z), hb.x, gh1); gh1 = fmaf(bfhi(wb.z), hb.y, gh1);
                gh1 = fmaf(bflo(wb.w), hb.z, gh1); gh1 = fmaf(bfhi(wb.w), hb.w, gh1);
            }
            s_gi[r0] = gi0; s_gi[r1] = gi1;
            s_gh[r0] = gh0; s_gh[r1] = gh1;
        }
        __syncthreads();
        // ---- GRU epilogue (biases already inside s_gi/s_gh) ----
        if (tid < D) {
            const int t = tid;
            float r  = sigmoidf_(s_gi[t] + s_gh[t]);
            float z  = sigmoidf_(s_gi[D + t] + s_gh[D + t]);
            float nn = tanhf(s_gi[2 * D + t] + r * s_gh[2 * D + t]);
            float hn = (1.f - z) * nn + z * s_h[t];
            s_h[t] = hn;
            s_q[t] = hn;                  // q part of q_star
        }
        __syncthreads();                  // also drains vmcnt: trips 0,1 resident

        // ---- flash attention: LDS-staged, barrier-free, counted-vmcnt ----
        q0 = ((const float4*)s_h)[s];          // cols 4s..4s+3
        q1 = ((const float4*)s_h)[16 + s];     // cols 64+4s..64+4s+3
        m_run = NEG_HUGE; l_run = 0.f;
        acc0 = make_float4(0.f, 0.f, 0.f, 0.f);
        acc1 = make_float4(0.f, 0.f, 0.f, 0.f);

        if (FT > 0) {
            int t = 0;
            while (true) {
                {   // process trip t from bufA
                    TripV T = lds_read_trip(laA);
                    const bool st = (t + 2 < FT);
                    if (st) stage_trip(bufA, t + 2);
                    if (t == FT - 1) { computeM(T, t); break; }
                    compute(T);
                    if (st) { WAITVM8(); } else { WAITVM0(); }
                    ++t;
                }
                {   // process trip t from bufB
                    TripV T = lds_read_trip(laB);
                    const bool st = (t + 2 < FT);
                    if (st) stage_trip(bufB, t + 2);
                    if (t == FT - 1) { computeM(T, t); break; }
                    compute(T);
                    if (st) { WAITVM8(); } else { WAITVM0(); }
                    ++t;
                }
            }
        }

        if (s == 0) { sm[g] = m_run; sl[g] = l_run; }
        __syncthreads();

        // ---- combine 16 group partials (every lane, 4-shfl tree) ----
        {
            const float mv = sm[s];
            const float lv = sl[s];
            float M = mv;
            M = fmaxf(M, __shfl_xor(M, 1, 64));
            M = fmaxf(M, __shfl_xor(M, 2, 64));
            M = fmaxf(M, __shfl_xor(M, 4, 64));
            M = fmaxf(M, __shfl_xor(M, 8, 64));
            float term = lv * __expf(mv - M);     // sentinel-safe: lv==0 there
            term += __shfl_xor(term, 1, 64);
            term += __shfl_xor(term, 2, 64);
            term += __shfl_xor(term, 4, 64);
            term += __shfl_xor(term, 8, 64);
            const float inv = 1.f / (term + 1e-16f);
            const float fac = __expf(m_run - M) * inv;  // sentinel-safe
            acc0.x *= fac; acc0.y *= fac; acc0.z *= fac; acc0.w *= fac;
            acc1.x *= fac; acc1.y *= fac; acc1.z *= fac; acc1.w *= fac;
        }
        // ---- sum the 4 groups within each wave (lanes s, s^16, s^32, s^48) --
        acc0.x += __shfl_xor(acc0.x, 16, 64); acc0.y += __shfl_xor(acc0.y, 16, 64);
        acc0.z += __shfl_xor(acc0.z, 16, 64); acc0.w += __shfl_xor(acc0.w, 16, 64);
        acc1.x += __shfl_xor(acc1.x, 16, 64); acc1.y += __shfl_xor(acc1.y, 16, 64);
        acc1.z += __shfl_xor(acc1.z, 16, 64); acc1.w += __shfl_xor(acc1.w, 16, 64);
        acc0.x += __shfl_xor(acc0.x, 32, 64); acc0.y += __shfl_xor(acc0.y, 32, 64);
        acc0.z += __shfl_xor(acc0.z, 32, 64); acc0.w += __shfl_xor(acc0.w, 32, 64);
        acc1.x += __shfl_xor(acc1.x, 32, 64); acc1.y += __shfl_xor(acc1.y, 32, 64);
        acc1.z += __shfl_xor(acc1.z, 32, 64); acc1.w += __shfl_xor(acc1.w, 32, 64);

        if ((tid & 63) < 16) {
            *(float4*)&rpart[wv][s4]      = acc0;
            *(float4*)&rpart[wv][64 + s4] = acc1;
        }
        __syncthreads();
        if (tid < D) {
            float v = (rpart[0][tid] + rpart[1][tid]) + (rpart[2][tid] + rpart[3][tid]);
            s_q[D + tid] = v;             // r part of q_star (already /L)
        }
        __syncthreads();                  // s_q complete for next GRU / output
    }

    // ---- write q_star row (s_q is exactly [q | r]) ----
    if (tid < 2 * D) out[(size_t)b * (2 * D) + tid] = s_q[tid];
}

// ---------------------------------------------------------------------------
extern "C" void kernel_launch(void* const* d_in, const int* in_sizes, int n_in,
                              void* d_out, int out_size, void* d_ws, size_t ws_size,
                              hipStream_t stream) {
    const float* x    = (const float*)d_in[0];
    const int*   batch= (const int*)d_in[1];
    // d_in[2] = batch_size scalar (fixed at B=512 compile time)
    const float* Wih  = (const float*)d_in[3];
    const float* Whh  = (const float*)d_in[4];
    const float* bih  = (const float*)d_in[5];
    const float* bhh  = (const float*)d_in[6];
    const int n = in_sizes[0] / D;        // 200000

    // workspace: seg (4 KB pad) | wih_bf (192 KB) | whh_bf (96 KB)
    char* ws = (char*)d_ws;
    int* seg = (int*)ws;
    unsigned short* wih_bf = (unsigned short*)(ws + 4096);
    unsigned short* whh_bf = (unsigned short*)(ws + 4096 + (size_t)NW_IH * 2);

    const int total = NW_IH + NW_HH;      // 147456 >= B+1, covers seg too
    k_prep<<<(total + 255) / 256, 256, 0, stream>>>(Wih, Whh, batch, n, wih_bf, whh_bf, seg);
    k_set2set<<<B, 256, 0, stream>>>(x, wih_bf, whh_bf, bih, bhh, seg, (float*)d_out);
}

// Round 10
// 216.620 us; speedup vs baseline: 1.5857x; 1.0076x over previous
//
#include <hip/hip_runtime.h>
#include <math.h>
#include <float.h>

constexpr int D = 128;       // in_channels
constexpr int B = 512;       // batch_size (graphs)
constexpr int STEPS = 3;
constexpr int NW_IH = 3 * D * 2 * D;   // 98304 elems, Wih [3D][2D]
constexpr int NW_HH = 3 * D * D;       // 49152 elems, Whh [3D][D]
constexpr float NEG_HUGE = -3.402823466e38f;   // -FLT_MAX sentinel (finite: no NaN paths)

typedef float f32x4 __attribute__((ext_vector_type(4)));
typedef __attribute__((address_space(1))) unsigned int gu32;
typedef __attribute__((address_space(3))) unsigned int lu32;
typedef __attribute__((address_space(3))) const unsigned char lchar;

__device__ __forceinline__ float sigmoidf_(float x) { return 1.f / (1.f + __expf(-x)); }
// bf16 pair unpack from a uint: low halfword / high halfword -> float (exact)
__device__ __forceinline__ float bflo(unsigned int u) { return __uint_as_float(u << 16); }
__device__ __forceinline__ float bfhi(unsigned int u) { return __uint_as_float(u & 0xffff0000u); }
__device__ __forceinline__ unsigned short f2bf_rn(float f) {
    unsigned int u = __float_as_uint(f);
    u += 0x7fffu + ((u >> 16) & 1u);    // round-to-nearest-even
    return (unsigned short)(u >> 16);
}
__device__ __forceinline__ int imin_(int a, int b) { return a < b ? a : b; }

// ---- DPP 16-lane reductions (VALU pipe, not LDS) ----
// xor1 = quad_perm[1,0,3,2] = 0xB1 ; xor2 = quad_perm[2,3,0,1] = 0x4E
// row_ror:4 = 0x124 ; row_ror:8 = 0x128  (DPP row = 16 lanes, group-aligned)
// Rotation-sum == butterfly-sum for commutative ops; every lane gets the total.
#define DPP_F(v, ctrl) \
    __int_as_float(__builtin_amdgcn_update_dpp(0, __float_as_int(v), ctrl, 0xF, 0xF, false))
#define DPP_RED16(v, OP) do {                       \
    v = OP(v, DPP_F(v, 0xB1));                      \
    v = OP(v, DPP_F(v, 0x4E));                      \
    v = OP(v, DPP_F(v, 0x124));                     \
    v = OP(v, DPP_F(v, 0x128));                     \
} while (0)
#define OP_ADD(a, b) ((a) + (b))
#define OP_MAX(a, b) fmaxf((a), (b))

// async 16B/lane global->LDS; LDS dest is wave-uniform base, HW adds lane*16
__device__ __forceinline__ void gll16(const float* g, float* l) {
    __builtin_amdgcn_global_load_lds((const gu32*)g, (lu32*)l, 16, 0, 0);
}
// byte offset of an LDS pointer (AS3 pointers are 32-bit)
__device__ __forceinline__ unsigned lds_lo(const void* p) {
    return (unsigned)(unsigned long long)(lchar*)p;
}
#define WAITVM8() asm volatile("s_waitcnt vmcnt(8)" ::: "memory")
#define WAITVM0() asm volatile("s_waitcnt vmcnt(0)" ::: "memory")

// ---------------------------------------------------------------------------
// K0 (prep): weights fp32 -> bf16 (RN), row-major, plus segment bounds via
// binary search on sorted batch[] (seg[g] = first index with batch[i] >= g).
// ---------------------------------------------------------------------------
__global__ __launch_bounds__(256) void k_prep(const float* __restrict__ Wih,
        const float* __restrict__ Whh, const int* __restrict__ batch, int n,
        unsigned short* __restrict__ wih_bf, unsigned short* __restrict__ whh_bf,
        int* __restrict__ seg) {
    int i = blockIdx.x * blockDim.x + threadIdx.x;
    if (i < NW_IH) wih_bf[i] = f2bf_rn(Wih[i]);
    else if (i < NW_IH + NW_HH) whh_bf[i - NW_IH] = f2bf_rn(Whh[i - NW_IH]);
    if (i <= B) {
        int lo = 0, hi = n;
        while (lo < hi) { int mid = (lo + hi) >> 1; if (batch[mid] < i) lo = mid + 1; else hi = mid; }
        seg[i] = lo;
    }
}

// ---------------------------------------------------------------------------
// K1 (fused Set2Set): one block of 256 threads (4 waves) per graph.
// R9 post-mortem: LDS-staged pipeline landed clean (no spills, counted vmcnt)
// but was NEUTRAL -> attention is not in-flight-capacity-bound (and R7 showed
// it's not BW-bound). Pipe accounting: the 16 __shfl_xor per trip lower to
// ds_swizzle/bpermute on the SAME per-CU LDS pipe as the staging ds_reads,
// and sit on the serial critical path. R10 moves all within-16-lane
// reductions to the VALU via DPP (quad_perm + row_ror) - zero LDS traffic:
//   * compute_core: 16 shfl -> 16 v_add_dpp.
//   * combine phase: max/sum over 16 partials via DPP (cross-row xor16/32
//     folds stay __shfl_xor).
// Everything else byte-identical to R9 (verified 93.5us).
// ---------------------------------------------------------------------------
struct TripV { f32x4 a0, a1, b0, b1, c0, c1, d0, d1; };

__device__ __forceinline__ TripV lds_read_trip(unsigned la) {
    TripV T;
    asm volatile(
        "ds_read_b128 %0, %8 offset:0\n\t"
        "ds_read_b128 %1, %8 offset:1024\n\t"
        "ds_read_b128 %2, %8 offset:2048\n\t"
        "ds_read_b128 %3, %8 offset:3072\n\t"
        "ds_read_b128 %4, %8 offset:4096\n\t"
        "ds_read_b128 %5, %8 offset:5120\n\t"
        "ds_read_b128 %6, %8 offset:6144\n\t"
        "ds_read_b128 %7, %8 offset:7168\n\t"
        "s_waitcnt lgkmcnt(0)"
        : "=&v"(T.a0), "=&v"(T.a1), "=&v"(T.b0), "=&v"(T.b1),
          "=&v"(T.c0), "=&v"(T.c1), "=&v"(T.d0), "=&v"(T.d1)
        : "v"(la));
    __builtin_amdgcn_sched_barrier(0);
    return T;
}

__global__ __launch_bounds__(256, 2) void k_set2set(
        const float* __restrict__ x,
        const unsigned short* __restrict__ wih_bf,
        const unsigned short* __restrict__ whh_bf,
        const float* __restrict__ bih, const float* __restrict__ bhh,
        const int* __restrict__ seg, float* __restrict__ out) {
    __shared__ __align__(16) float s_q[2 * D];    // q_star: [q | r]
    __shared__ __align__(16) float s_h[D];
    __shared__ float s_gi[3 * D], s_gh[3 * D];
    __shared__ float sm[16], sl[16];
    __shared__ __align__(16) float rpart[4][D];   // 2 KB
    __shared__ __align__(16) float s_bufA[4][2048];   // 32 KB: per-wave trip buf A
    __shared__ __align__(16) float s_bufB[4][2048];   // 32 KB: per-wave trip buf B

    const int b = blockIdx.x;
    const int tid = threadIdx.x;
    const int start = seg[b], end = seg[b + 1];
    const int g = tid >> 4;               // node-group id 0..15
    const int s = tid & 15;               // sublane: cols [4s,4s+4) & [64+4s,64+4s+4)
    const int s4 = s * 4;
    const int wv = tid >> 6;              // wave id 0..3
    const int lane = tid & 63;

    const int len = end - start;
    const int FT = (len + 63) >> 6;       // trips incl. masked last
    const int gbase = start + g;
    const int eclamp = (len > 0) ? end - 1 : start;

    float* bufA = &s_bufA[wv][0];
    float* bufB = &s_bufB[wv][0];
    const unsigned laA = lds_lo(bufA) + lane * 16;
    const unsigned laB = lds_lo(bufB) + lane * 16;

    float m_run, l_run;
    float4 acc0, acc1;
    float4 q0, q1;

    auto stage_trip = [&](float* buf, int t) {
        const int n0 = gbase + (t << 6);
        const float* p0 = x + ((size_t)imin_(n0,      eclamp) << 7) + s4;
        const float* p1 = x + ((size_t)imin_(n0 + 16, eclamp) << 7) + s4;
        const float* p2 = x + ((size_t)imin_(n0 + 32, eclamp) << 7) + s4;
        const float* p3 = x + ((size_t)imin_(n0 + 48, eclamp) << 7) + s4;
        gll16(p0,      buf);
        gll16(p0 + 64, buf + 256);
        gll16(p1,      buf + 512);
        gll16(p1 + 64, buf + 768);
        gll16(p2,      buf + 1024);
        gll16(p2 + 64, buf + 1280);
        gll16(p3,      buf + 1536);
        gll16(p3 + 64, buf + 1792);
    };
    auto dot8 = [&](const f32x4& lo, const f32x4& hi) {
        float p = lo.x * q0.x;
        p = fmaf(lo.y, q0.y, p); p = fmaf(lo.z, q0.z, p); p = fmaf(lo.w, q0.w, p);
        p = fmaf(hi.x, q1.x, p); p = fmaf(hi.y, q1.y, p);
        p = fmaf(hi.z, q1.z, p); p = fmaf(hi.w, q1.w, p);
        return p;
    };
    auto compute_core = [&](const TripV& T, bool masked, int t) {
        float p0 = dot8(T.a0, T.a1);
        float p1 = dot8(T.b0, T.b1);
        float p2 = dot8(T.c0, T.c1);
        float p3 = dot8(T.d0, T.d1);
        // 16-lane sums on the VALU pipe (DPP), zero LDS traffic
        DPP_RED16(p0, OP_ADD);
        DPP_RED16(p1, OP_ADD);
        DPP_RED16(p2, OP_ADD);
        DPP_RED16(p3, OP_ADD);
        bool m0 = true, m1 = true, m2 = true, m3 = true;
        float h0 = p0, h1 = p1, h2 = p2, h3 = p3;
        if (masked) {
            const int n0 = gbase + (t << 6);
            m0 = n0 < end; m1 = n0 + 16 < end; m2 = n0 + 32 < end; m3 = n0 + 48 < end;
            h0 = m0 ? p0 : NEG_HUGE; h1 = m1 ? p1 : NEG_HUGE;
            h2 = m2 ? p2 : NEG_HUGE; h3 = m3 ? p3 : NEG_HUGE;
        }
        float nm = fmaxf(m_run, fmaxf(fmaxf(h0, h1), fmaxf(h2, h3)));
        float sc = __expf(m_run - nm);            // 0 while m_run sentinel
        float e0 = __expf(p0 - nm), e1 = __expf(p1 - nm);
        float e2 = __expf(p2 - nm), e3 = __expf(p3 - nm);
        if (masked) {
            e0 = m0 ? e0 : 0.f; e1 = m1 ? e1 : 0.f;
            e2 = m2 ? e2 : 0.f; e3 = m3 ? e3 : 0.f;
        }
        l_run = fmaf(l_run, sc, (e0 + e1) + (e2 + e3));
        acc0.x = fmaf(acc0.x, sc, fmaf(e0, T.a0.x, fmaf(e1, T.b0.x, fmaf(e2, T.c0.x, e3 * T.d0.x))));
        acc0.y = fmaf(acc0.y, sc, fmaf(e0, T.a0.y, fmaf(e1, T.b0.y, fmaf(e2, T.c0.y, e3 * T.d0.y))));
        acc0.z = fmaf(acc0.z, sc, fmaf(e0, T.a0.z, fmaf(e1, T.b0.z, fmaf(e2, T.c0.z, e3 * T.d0.z))));
        acc0.w = fmaf(acc0.w, sc, fmaf(e0, T.a0.w, fmaf(e1, T.b0.w, fmaf(e2, T.c0.w, e3 * T.d0.w))));
        acc1.x = fmaf(acc1.x, sc, fmaf(e0, T.a1.x, fmaf(e1, T.b1.x, fmaf(e2, T.c1.x, e3 * T.d1.x))));
        acc1.y = fmaf(acc1.y, sc, fmaf(e0, T.a1.y, fmaf(e1, T.b1.y, fmaf(e2, T.c1.y, e3 * T.d1.y))));
        acc1.z = fmaf(acc1.z, sc, fmaf(e0, T.a1.z, fmaf(e1, T.b1.z, fmaf(e2, T.c1.z, e3 * T.d1.z))));
        acc1.w = fmaf(acc1.w, sc, fmaf(e0, T.a1.w, fmaf(e1, T.b1.w, fmaf(e2, T.c1.w, e3 * T.d1.w))));
        m_run = nm;
    };
    auto compute  = [&](const TripV& T)        { compute_core(T, false, 0); };
    auto computeM = [&](const TripV& T, int t) { compute_core(T, true,  t); };

    if (tid < 2 * D) s_q[tid] = 0.f;
    if (tid < D) s_h[tid] = 0.f;
    __syncthreads();

    for (int step = 0; step < STEPS; ++step) {
        // prologue: stage trips 0,1 async (x step-invariant; no LDS-state dep).
        // The GRU-epilogue barrier's vmcnt(0) drain makes them resident for free.
        if (FT > 0) stage_trip(bufA, 0);
        if (FT > 1) stage_trip(bufB, 1);

        if (step == 0) {
            // q_star = 0 and h = 0: gi = b_ih, gh = b_hh exactly -> skip matvec
            for (int i = tid; i < 3 * D; i += 256) { s_gi[i] = bih[i]; s_gh[i] = bhh[i]; }
        } else if (tid < 192) {
            // ---- GRU gate rows: threads 0..191, rows 2t and 2t+1 (ILP 2) ----
            const int r0 = tid * 2, r1 = r0 + 1;
            float gi0 = bih[r0], gi1 = bih[r1];
            float gh0 = bhh[r0], gh1 = bhh[r1];
            const float4* q4 = (const float4*)s_q;
            const float4* h4 = (const float4*)s_h;
            const uint4* w0 = (const uint4*)(wih_bf + (size_t)r0 * (2 * D));
            const uint4* w1 = (const uint4*)(wih_bf + (size_t)r1 * (2 * D));
#pragma unroll 4
            for (int c = 0; c < 32; ++c) {        // 256 cols of Wih, 8/iter
                uint4 wa = w0[c], wb = w1[c];
                float4 qa = q4[2 * c], qb = q4[2 * c + 1];
                gi0 = fmaf(bflo(wa.x), qa.x, gi0); gi0 = fmaf(bfhi(wa.x), qa.y, gi0);
                gi0 = fmaf(bflo(wa.y), qa.z, gi0); gi0 = fmaf(bfhi(wa.y), qa.w, gi0);
                gi0 = fmaf(bflo(wa.z), qb.x, gi0); gi0 = fmaf(bfhi(wa.z), qb.y, gi0);
                gi0 = fmaf(bflo(wa.w), qb.z, gi0); gi0 = fmaf(bfhi(wa.w), qb.w, gi0);
                gi1 = fmaf(bflo(wb.x), qa.x, gi1); gi1 = fmaf(bfhi(wb.x), qa.y, gi1);
                gi1 = fmaf(bflo(wb.y), qa.z, gi1); gi1 = fmaf(bfhi(wb.y), qa.w, gi1);
                gi1 = fmaf(bflo(wb.z), qb.x, gi1); gi1 = fmaf(bfhi(wb.z), qb.y, gi1);
                gi1 = fmaf(bflo(wb.w), qb.z, gi1); gi1 = fmaf(bfhi(wb.w), qb.w, gi1);
            }
            const uint4* v0 = (const uint4*)(whh_bf + (size_t)r0 * D);
            const uint4* v1 = (const uint4*)(whh_bf + (size_t)r1 * D);
#pragma unroll 4
            for (int c = 0; c < 16; ++c) {        // 128 cols of Whh
                uint4 wa = v0[c], wb = v1[c];
                float4 ha = h4[2 * c], hb = h4[2 * c + 1];
                gh0 = fmaf(bflo(wa.x), ha.x, gh0); gh0 = fmaf(bfhi(wa.x), ha.y, gh0);
                gh0 = fmaf(bflo(wa.y), ha.z, gh0); gh0 = fmaf(bfhi(wa.y), ha.w, gh0);
                gh0 = fmaf(bflo(wa.z), hb.x, gh0); gh0 = fmaf(bfhi(wa.z), hb.y, gh0);
                gh0 = fmaf(bflo(wa.w), hb.z, gh0); gh0 = fmaf(bfhi(wa.w), hb.w, gh0);
                gh1 = fmaf(bflo(wb.x), ha.x, gh1); gh1 = fmaf(bfhi(wb.x), ha.y, gh1);
                gh1 = fmaf(bflo(wb.y), ha.z, gh1); gh1 = fmaf(bfhi(wb.y), ha.w, gh1);
                gh1 = fmaf(bflo(wb.z), hb.x, gh1); gh1 = fmaf(bfhi(wb.z), hb.y, gh1);
                gh1 = fmaf(bflo(wb.w), hb.z, gh1); gh1 = fmaf(bfhi(wb.w), hb.w, gh1);
            }
            s_gi[r0] = gi0; s_gi[r1] = gi1;
            s_gh[r0] = gh0; s_gh[r1] = gh1;
        }
        __syncthreads();
        // ---- GRU epilogue (biases already inside s_gi/s_gh) ----
        if (tid < D) {
            const int t = tid;
            float r  = sigmoidf_(s_gi[t] + s_gh[t]);
            float z  = sigmoidf_(s_gi[D + t] + s_gh[D + t]);
            float nn = tanhf(s_gi[2 * D + t] + r * s_gh[2 * D + t]);
            float hn = (1.f - z) * nn + z * s_h[t];
            s_h[t] = hn;
            s_q[t] = hn;                  // q part of q_star
        }
        __syncthreads();                  // also drains vmcnt: trips 0,1 resident

        // ---- flash attention: LDS-staged, barrier-free, counted-vmcnt ----
        q0 = ((const float4*)s_h)[s];          // cols 4s..4s+3
        q1 = ((const float4*)s_h)[16 + s];     // cols 64+4s..64+4s+3
        m_run = NEG_HUGE; l_run = 0.f;
        acc0 = make_float4(0.f, 0.f, 0.f, 0.f);
        acc1 = make_float4(0.f, 0.f, 0.f, 0.f);

        if (FT > 0) {
            int t = 0;
            while (true) {
                {   // process trip t from bufA
                    TripV T = lds_read_trip(laA);
                    const bool st = (t + 2 < FT);
                    if (st) stage_trip(bufA, t + 2);
                    if (t == FT - 1) { computeM(T, t); break; }
                    compute(T);
                    if (st) { WAITVM8(); } else { WAITVM0(); }
                    ++t;
                }
                {   // process trip t from bufB
                    TripV T = lds_read_trip(laB);
                    const bool st = (t + 2 < FT);
                    if (st) stage_trip(bufB, t + 2);
                    if (t == FT - 1) { computeM(T, t); break; }
                    compute(T);
                    if (st) { WAITVM8(); } else { WAITVM0(); }
                    ++t;
                }
            }
        }

        if (s == 0) { sm[g] = m_run; sl[g] = l_run; }
        __syncthreads();

        // ---- combine 16 group partials (DPP within row; xor16/32 stay shfl) --
        {
            const float mv = sm[s];
            const float lv = sl[s];
            float M = mv;
            DPP_RED16(M, OP_MAX);
            float term = lv * __expf(mv - M);     // sentinel-safe: lv==0 there
            DPP_RED16(term, OP_ADD);
            const float inv = 1.f / (term + 1e-16f);
            const float fac = __expf(m_run - M) * inv;  // sentinel-safe
            acc0.x *= fac; acc0.y *= fac; acc0.z *= fac; acc0.w *= fac;
            acc1.x *= fac; acc1.y *= fac; acc1.z *= fac; acc1.w *= fac;
        }
        // ---- sum the 4 groups within each wave (lanes s, s^16, s^32, s^48) --
        acc0.x += __shfl_xor(acc0.x, 16, 64); acc0.y += __shfl_xor(acc0.y, 16, 64);
        acc0.z += __shfl_xor(acc0.z, 16, 64); acc0.w += __shfl_xor(acc0.w, 16, 64);
        acc1.x += __shfl_xor(acc1.x, 16, 64); acc1.y += __shfl_xor(acc1.y, 16, 64);
        acc1.z += __shfl_xor(acc1.z, 16, 64); acc1.w += __shfl_xor(acc1.w, 16, 64);
        acc0.x += __shfl_xor(acc0.x, 32, 64); acc0.y += __shfl_xor(acc0.y, 32, 64);
        acc0.z += __shfl_xor(acc0.z, 32, 64); acc0.w += __shfl_xor(acc0.w, 32, 64);
        acc1.x += __shfl_xor(acc1.x, 32, 64); acc1.y += __shfl_xor(acc1.y, 32, 64);
        acc1.z += __shfl_xor(acc1.z, 32, 64); acc1.w += __shfl_xor(acc1.w, 32, 64);

        if ((tid & 63) < 16) {
            *(float4*)&rpart[wv][s4]      = acc0;
            *(float4*)&rpart[wv][64 + s4] = acc1;
        }
        __syncthreads();
        if (tid < D) {
            float v = (rpart[0][tid] + rpart[1][tid]) + (rpart[2][tid] + rpart[3][tid]);
            s_q[D + tid] = v;             // r part of q_star (already /L)
        }
        __syncthreads();                  // s_q complete for next GRU / output
    }

    // ---- write q_star row (s_q is exactly [q | r]) ----
    if (tid < 2 * D) out[(size_t)b * (2 * D) + tid] = s_q[tid];
}

// ---------------------------------------------------------------------------
extern "C" void kernel_launch(void* const* d_in, const int* in_sizes, int n_in,
                              void* d_out, int out_size, void* d_ws, size_t ws_size,
                              hipStream_t stream) {
    const float* x    = (const float*)d_in[0];
    const int*   batch= (const int*)d_in[1];
    // d_in[2] = batch_size scalar (fixed at B=512 compile time)
    const float* Wih  = (const float*)d_in[3];
    const float* Whh  = (const float*)d_in[4];
    const float* bih  = (const float*)d_in[5];
    const float* bhh  = (const float*)d_in[6];
    const int n = in_sizes[0] / D;        // 200000

    // workspace: seg (4 KB pad) | wih_bf (192 KB) | whh_bf (96 KB)
    char* ws = (char*)d_ws;
    int* seg = (int*)ws;
    unsigned short* wih_bf = (unsigned short*)(ws + 4096);
    unsigned short* whh_bf = (unsigned short*)(ws + 4096 + (size_t)NW_IH * 2);

    const int total = NW_IH + NW_HH;      // 147456 >= B+1, covers seg too
    k_prep<<<(total + 255) / 256, 256, 0, stream>>>(Wih, Whh, batch, n, wih_bf, whh_bf, seg);
    k_set2set<<<B, 256, 0, stream>>>(x, wih_bf, whh_bf, bih, bhh, seg, (float*)d_out);
}